// Round 6
// baseline (331.306 us; speedup 1.0000x reference)
//
#include <hip/hip_runtime.h>

#define GM_EPS 1e-8f
#define BLK 128   // 128 divides n = 2,000,000 exactly -> vector path has no tail

__global__ __launch_bounds__(BLK) void gaussian_merge_kernel(
    const float* __restrict__ loc1,
    const float* __restrict__ scale1,
    const float* __restrict__ rot1,
    const float* __restrict__ loc2,
    const float* __restrict__ scale2,
    const float* __restrict__ rot2,
    float* __restrict__ out_loc,   // [n,3]
    float* __restrict__ out_cov,   // [n,3,3]
    int n)
{
    // LDS staging: converts stride-12B / stride-36B per-lane global access into
    // perfectly coalesced float4 streams. 15360 B/block -> 10 blocks/CU.
    __shared__ alignas(16) float sR1[BLK * 9];
    __shared__ alignas(16) float sR2[BLK * 9];
    __shared__ alignas(16) float sL1[BLK * 3];
    __shared__ alignas(16) float sL2[BLK * 3];
    __shared__ alignas(16) float sS1[BLK * 3];
    __shared__ alignas(16) float sS2[BLK * 3];

    const int  tid       = threadIdx.x;
    const long blockBase = (long)blockIdx.x * BLK;
    const int  cnt       = (int)((blockBase + BLK <= (long)n) ? BLK : ((long)n - blockBase));

    // ---------------- cooperative staged loads ----------------
    if (cnt == BLK) {
        // rot chunks: BLK*9 floats = 288 float4 (bases are 16B-aligned: blockBase*36B)
        const float4* r1 = (const float4*)(rot1 + blockBase * 9);
        const float4* r2 = (const float4*)(rot2 + blockBase * 9);
        float4* d1 = (float4*)sR1;
        float4* d2 = (float4*)sR2;
        for (int j = tid; j < BLK * 9 / 4; j += BLK) { d1[j] = r1[j]; d2[j] = r2[j]; }

        // loc/scale chunks: BLK*3 floats = 96 float4 each
        const float4* p1 = (const float4*)(loc1   + blockBase * 3);
        const float4* p2 = (const float4*)(loc2   + blockBase * 3);
        const float4* q1 = (const float4*)(scale1 + blockBase * 3);
        const float4* q2 = (const float4*)(scale2 + blockBase * 3);
        float4* e1 = (float4*)sL1;
        float4* e2 = (float4*)sL2;
        float4* f1 = (float4*)sS1;
        float4* f2 = (float4*)sS2;
        if (tid < BLK * 3 / 4) {
            e1[tid] = p1[tid]; e2[tid] = p2[tid];
            f1[tid] = q1[tid]; f2[tid] = q2[tid];
        }
    } else {
        // guarded scalar tail path (never taken at n = 2M)
        for (int j = tid; j < cnt * 9; j += BLK) {
            sR1[j] = rot1[blockBase * 9 + j];
            sR2[j] = rot2[blockBase * 9 + j];
        }
        for (int j = tid; j < cnt * 3; j += BLK) {
            sL1[j] = loc1[blockBase * 3 + j];
            sL2[j] = loc2[blockBase * 3 + j];
            sS1[j] = scale1[blockBase * 3 + j];
            sS2[j] = scale2[blockBase * 3 + j];
        }
    }
    __syncthreads();

    // ---------------- per-thread compute (registers only) ----------------
    // Each thread's LDS region [tid*9, tid*9+9) / [tid*3, tid*3+3) is private:
    // reading it then overwriting it with results needs no barrier.
    if (tid < cnt) {
        float R1[9], R2[9], l1[3], l2[3], s1[3], s2[3];
#pragma unroll
        for (int k = 0; k < 9; ++k) { R1[k] = sR1[tid * 9 + k]; R2[k] = sR2[tid * 9 + k]; }
#pragma unroll
        for (int k = 0; k < 3; ++k) {
            l1[k] = sL1[tid * 3 + k];
            l2[k] = sL2[tid * 3 + k];
            s1[k] = sS1[tid * 3 + k];
            s2[k] = sS2[tid * 3 + k];
        }

        // c1 = R1 diag(s1) R1^T ; S = c1 + c2 + eps*I
        float c1[3][3], S[3][3];
#pragma unroll
        for (int a = 0; a < 3; ++a) {
#pragma unroll
            for (int b = 0; b < 3; ++b) {
                float v1 = 0.f, v2 = 0.f;
#pragma unroll
                for (int k = 0; k < 3; ++k) {
                    v1 = fmaf(R1[a * 3 + k] * s1[k], R1[b * 3 + k], v1);
                    v2 = fmaf(R2[a * 3 + k] * s2[k], R2[b * 3 + k], v2);
                }
                c1[a][b] = v1;
                S[a][b]  = v1 + v2 + (a == b ? GM_EPS : 0.f);
            }
        }

        // Sinv = inv(S), adjugate of symmetric 3x3
        const float m00 = S[0][0], m01 = S[0][1], m02 = S[0][2];
        const float m11 = S[1][1], m12 = S[1][2], m22 = S[2][2];
        const float A0 = m11 * m22 - m12 * m12;
        const float A1 = m02 * m12 - m01 * m22;
        const float A2 = m01 * m12 - m02 * m11;
        const float det    = m00 * A0 + m01 * A1 + m02 * A2;
        const float invdet = 1.0f / det;

        float Sinv[3][3];
        Sinv[0][0] = A0 * invdet;
        Sinv[0][1] = A1 * invdet;
        Sinv[0][2] = A2 * invdet;
        Sinv[1][1] = (m00 * m22 - m02 * m02) * invdet;
        Sinv[1][2] = (m01 * m02 - m00 * m12) * invdet;
        Sinv[2][2] = (m00 * m11 - m01 * m01) * invdet;
        Sinv[1][0] = Sinv[0][1];
        Sinv[2][0] = Sinv[0][2];
        Sinv[2][1] = Sinv[1][2];

        // K = c1 @ Sinv
        float K[3][3];
#pragma unroll
        for (int a = 0; a < 3; ++a) {
#pragma unroll
            for (int b = 0; b < 3; ++b) {
                float v = 0.f;
#pragma unroll
                for (int k = 0; k < 3; ++k)
                    v = fmaf(c1[a][k], Sinv[k][b], v);
                K[a][b] = v;
            }
        }

        // loc_new = loc1 + K @ (loc2 - loc1)  -> stage into sL1
        const float d0 = l2[0] - l1[0], d1 = l2[1] - l1[1], d2 = l2[2] - l1[2];
#pragma unroll
        for (int a = 0; a < 3; ++a) {
            float v = fmaf(K[a][0], d0, fmaf(K[a][1], d1, K[a][2] * d2));
            sL1[tid * 3 + a] = l1[a] + v;
        }

        // cov_new = c1 + K @ c1  -> stage into sR1
#pragma unroll
        for (int a = 0; a < 3; ++a) {
#pragma unroll
            for (int b = 0; b < 3; ++b) {
                float v = 0.f;
#pragma unroll
                for (int k = 0; k < 3; ++k)
                    v = fmaf(K[a][k], c1[k][b], v);
                sR1[tid * 9 + a * 3 + b] = c1[a][b] + v;
            }
        }
    }
    __syncthreads();

    // ---------------- cooperative staged stores ----------------
    if (cnt == BLK) {
        // out_loc base: blockBase*12B (16B-aligned since BLK*3*4 = 1536B);
        // out_cov base: n*3 floats (24MB, 16B-aligned) + blockBase*36B.
        float4* ol = (float4*)(out_loc + blockBase * 3);
        float4* oc = (float4*)(out_cov + blockBase * 9);
        const float4* sl = (const float4*)sL1;
        const float4* sc = (const float4*)sR1;
        for (int j = tid; j < BLK * 9 / 4; j += BLK) oc[j] = sc[j];
        if (tid < BLK * 3 / 4) ol[tid] = sl[tid];
    } else {
        for (int j = tid; j < cnt * 9; j += BLK) out_cov[blockBase * 9 + j] = sR1[j];
        for (int j = tid; j < cnt * 3; j += BLK) out_loc[blockBase * 3 + j] = sL1[j];
    }
}

extern "C" void kernel_launch(void* const* d_in, const int* in_sizes, int n_in,
                              void* d_out, int out_size, void* d_ws, size_t ws_size,
                              hipStream_t stream) {
    const float* loc1   = (const float*)d_in[0];
    const float* scale1 = (const float*)d_in[1];
    const float* rot1   = (const float*)d_in[2];
    const float* loc2   = (const float*)d_in[3];
    const float* scale2 = (const float*)d_in[4];
    const float* rot2   = (const float*)d_in[5];
    // d_in[6], d_in[7] = cov1/cov2 placeholders: reference recomputes them.

    const int n = in_sizes[0] / 3;  // loc1 is [n,3]

    float* out     = (float*)d_out;
    float* out_loc = out;                  // [n,3]
    float* out_cov = out + (size_t)n * 3;  // [n,3,3]

    const int grid = (n + BLK - 1) / BLK;
    gaussian_merge_kernel<<<grid, BLK, 0, stream>>>(
        loc1, scale1, rot1, loc2, scale2, rot2, out_loc, out_cov, n);
}